// Round 1
// baseline (618.028 us; speedup 1.0000x reference)
//
#include <hip/hip_runtime.h>
#include <stdint.h>

// Shapes (fixed by reference): B=32, S=2048, D=1024.
#define BDIM 32
#define SDIM 2048
#define DDIM 1024
#define MDIM (BDIM * SDIM)   // 65536 rows of the GEMM

typedef __bf16 bf16x8 __attribute__((ext_vector_type(8)));
typedef float  f32x4  __attribute__((ext_vector_type(4)));

// ---------- helpers ----------

__device__ inline unsigned short f2bf(float f) {
  union { float f; unsigned u; } un; un.f = f;
  unsigned r = un.u + 0x7fffu + ((un.u >> 16) & 1u);   // RNE
  return (unsigned short)(r >> 16);
}

__device__ inline float fast_tanh(float x) {
  // tanh(x) = 1 - 2/(e^{2x}+1); exact limits at +-inf via __expf saturation
  float e = __expf(2.0f * x);
  return 1.0f - 2.0f / (e + 1.0f);
}

__device__ inline void gl_lds16(const unsigned short* g, unsigned short* l) {
  __builtin_amdgcn_global_load_lds(
      (__attribute__((address_space(1))) unsigned int*)(void*)(uintptr_t)g,
      (__attribute__((address_space(3))) unsigned int*)l,
      16, 0, 0);
}

// ---------- kernel 1: fp32 -> bf16 convert (8 elems/thread) ----------

__global__ __launch_bounds__(256) void cvt_kernel(const float* __restrict__ src,
                                                  unsigned short* __restrict__ dst) {
  size_t i = (size_t)blockIdx.x * 256 + threadIdx.x;
  const float4* s4 = (const float4*)src;
  float4 a = s4[2 * i];
  float4 b = s4[2 * i + 1];
  uint4 o;
  o.x = (unsigned)f2bf(a.x) | ((unsigned)f2bf(a.y) << 16);
  o.y = (unsigned)f2bf(a.z) | ((unsigned)f2bf(a.w) << 16);
  o.z = (unsigned)f2bf(b.x) | ((unsigned)f2bf(b.y) << 16);
  o.w = (unsigned)f2bf(b.z) | ((unsigned)f2bf(b.w) << 16);
  ((uint4*)dst)[i] = o;
}

// ---------- kernel 2: bf16 GEMM (128x128 tile, 16x16x32 MFMA) ----------
// logits[m] += sum_n tanh( sum_k A[m][k]*W[n][k] ) * v[n]
// Grid: (M/128) * (N/128) = 512*8 = 4096 blocks; blockIdx = mt*8 + nt so the
// 8 N-tiles sharing one A-chunk are adjacent in dispatch (L2/L3 locality).

__global__ __launch_bounds__(256) void gemm_logits(
    const unsigned short* __restrict__ A,   // [M][1024] bf16 context
    const unsigned short* __restrict__ Bw,  // [1024][1024] bf16 W (row e, col d)
    const float* __restrict__ v,
    float* __restrict__ logits)             // [M], pre-zeroed
{
  __shared__ __align__(16) unsigned short Al[128 * 32];
  __shared__ __align__(16) unsigned short Bl[128 * 32];

  const int t  = threadIdx.x;
  const int mt = blockIdx.x >> 3;
  const int nt = blockIdx.x & 7;
  const int m0 = mt * 128;
  const int n0 = nt * 128;
  const int w    = t >> 6;
  const int lane = t & 63;
  const int wm = (w >> 1) * 64;   // wave row offset in tile
  const int wn = (w & 1) * 64;    // wave col offset in tile
  const int c = lane & 15;        // frag col
  const int q = lane >> 4;        // frag quad

  // v values for this wave's 4 column-frags (epilogue)
  float vv[4];
#pragma unroll
  for (int ni = 0; ni < 4; ++ni) vv[ni] = v[n0 + wn + ni * 16 + c];

  f32x4 acc[4][4] = {};

  // staging addresses: 128 rows x 32 bf16 (64 B/row); thread -> 16 B chunk
  const int srow = t >> 2;          // 0..63
  const int skel = (t & 3) * 8;     // element offset within row
  const unsigned short* ga0 = A  + (size_t)(m0 + srow) * DDIM + skel;
  const unsigned short* ga1 = A  + (size_t)(m0 + 64 + srow) * DDIM + skel;
  const unsigned short* gb0 = Bw + (size_t)(n0 + srow) * DDIM + skel;
  const unsigned short* gb1 = Bw + (size_t)(n0 + 64 + srow) * DDIM + skel;
  unsigned short* la0 = Al + w * 512;          // wave-uniform LDS bases
  unsigned short* la1 = Al + 2048 + w * 512;
  unsigned short* lb0 = Bl + w * 512;
  unsigned short* lb1 = Bl + 2048 + w * 512;

  for (int kt = 0; kt < 32; ++kt) {
    const int k0 = kt * 32;
    gl_lds16(ga0 + k0, la0);
    gl_lds16(ga1 + k0, la1);
    gl_lds16(gb0 + k0, lb0);
    gl_lds16(gb1 + k0, lb1);
    __syncthreads();   // compiler emits vmcnt(0) drain before s_barrier

    bf16x8 af[4], bfr[4];
#pragma unroll
    for (int mi = 0; mi < 4; ++mi)
      af[mi] = *(const bf16x8*)&Al[(wm + mi * 16 + c) * 32 + q * 8];
#pragma unroll
    for (int ni = 0; ni < 4; ++ni)
      bfr[ni] = *(const bf16x8*)&Bl[(wn + ni * 16 + c) * 32 + q * 8];

#pragma unroll
    for (int mi = 0; mi < 4; ++mi)
#pragma unroll
      for (int ni = 0; ni < 4; ++ni)
        acc[mi][ni] = __builtin_amdgcn_mfma_f32_16x16x32_bf16(
            af[mi], bfr[ni], acc[mi][ni], 0, 0, 0);

    __syncthreads();
  }

  // Epilogue: tanh, dot with v over this wave's 64 columns, reduce, atomicAdd.
  // C/D layout (16x16): col = lane&15, row = (lane>>4)*4 + reg.
#pragma unroll
  for (int mi = 0; mi < 4; ++mi) {
    float p0 = 0.f, p1 = 0.f, p2 = 0.f, p3 = 0.f;
#pragma unroll
    for (int ni = 0; ni < 4; ++ni) {
      const float vvn = vv[ni];
      p0 += fast_tanh(acc[mi][ni][0]) * vvn;
      p1 += fast_tanh(acc[mi][ni][1]) * vvn;
      p2 += fast_tanh(acc[mi][ni][2]) * vvn;
      p3 += fast_tanh(acc[mi][ni][3]) * vvn;
    }
#pragma unroll
    for (int mask = 1; mask <= 8; mask <<= 1) {
      p0 += __shfl_xor(p0, mask);
      p1 += __shfl_xor(p1, mask);
      p2 += __shfl_xor(p2, mask);
      p3 += __shfl_xor(p3, mask);
    }
    if (c == 0) {
      float* lp = logits + (m0 + wm + mi * 16 + q * 4);
      atomicAdd(lp + 0, p0);
      atomicAdd(lp + 1, p1);
      atomicAdd(lp + 2, p2);
      atomicAdd(lp + 3, p3);
    }
  }
}

// ---------- kernel 3: per-batch softmax (in place over logits) ----------

__global__ __launch_bounds__(256) void softmax_kernel(float* __restrict__ la) {
  const int b = blockIdx.x;
  const int t = threadIdx.x;
  float* p = la + (size_t)b * SDIM;
  float x[8];
#pragma unroll
  for (int i = 0; i < 8; ++i) x[i] = p[i * 256 + t];
  float m = x[0];
#pragma unroll
  for (int i = 1; i < 8; ++i) m = fmaxf(m, x[i]);
#pragma unroll
  for (int mask = 1; mask < 64; mask <<= 1) m = fmaxf(m, __shfl_xor(m, mask));
  __shared__ float redm[4], reds[4];
  const int w = t >> 6, lane = t & 63;
  if (lane == 0) redm[w] = m;
  __syncthreads();
  m = fmaxf(fmaxf(redm[0], redm[1]), fmaxf(redm[2], redm[3]));
  float e[8];
  float s = 0.f;
#pragma unroll
  for (int i = 0; i < 8; ++i) { e[i] = __expf(x[i] - m); s += e[i]; }
#pragma unroll
  for (int mask = 1; mask < 64; mask <<= 1) s += __shfl_xor(s, mask);
  if (lane == 0) reds[w] = s;
  __syncthreads();
  s = reds[0] + reds[1] + reds[2] + reds[3];
  const float inv = 1.0f / s;
#pragma unroll
  for (int i = 0; i < 8; ++i) p[i * 256 + t] = e[i] * inv;
}

// ---------- kernel 4: weighted context sum ----------
// wc[b][d] = sum_s attn[b][s] * ctx[b][s][d]; grid = 32 batches * 16 s-chunks

__global__ __launch_bounds__(256) void wsum_kernel(const float* __restrict__ ctx,
                                                   const float* __restrict__ attn,
                                                   float* __restrict__ wc) {
  const int b  = blockIdx.x >> 4;
  const int sc = blockIdx.x & 15;
  const int t  = threadIdx.x;
  const float* cp = ctx + ((size_t)b * SDIM + sc * 128) * DDIM + t * 4;
  const float* ap = attn + (size_t)b * SDIM + sc * 128;
  float4 acc = {0.f, 0.f, 0.f, 0.f};
  for (int s = 0; s < 128; ++s) {
    const float a = ap[s];
    const float4 cv = *(const float4*)(cp + (size_t)s * DDIM);
    acc.x += a * cv.x; acc.y += a * cv.y; acc.z += a * cv.z; acc.w += a * cv.w;
  }
  float* o = wc + (size_t)b * DDIM + t * 4;
  atomicAdd(o + 0, acc.x);
  atomicAdd(o + 1, acc.y);
  atomicAdd(o + 2, acc.z);
  atomicAdd(o + 3, acc.w);
}

// ---------- launch ----------

extern "C" void kernel_launch(void* const* d_in, const int* in_sizes, int n_in,
                              void* d_out, int out_size, void* d_ws, size_t ws_size,
                              hipStream_t stream) {
  const float* ctx = (const float*)d_in[0];   // [32,2048,1024] fp32
  const float* W   = (const float*)d_in[1];   // [1024,1024] fp32
  const float* v   = (const float*)d_in[2];   // [1024] fp32
  // d_in[3] = scalar b: softmax-invariant, unused.

  float* out_wc   = (float*)d_out;            // [32,1024]
  float* out_attn = out_wc + BDIM * DDIM;     // [32,2048] (logits, then attn)

  unsigned short* ctx_bf = (unsigned short*)d_ws;           // 128 MB
  unsigned short* W_bf   = ctx_bf + (size_t)MDIM * DDIM;    // 2 MB

  // zero wc (atomics target) and logits (atomics target)
  hipMemsetAsync(d_out, 0, (size_t)out_size * sizeof(float), stream);

  cvt_kernel<<<(MDIM * DDIM) / (256 * 8), 256, 0, stream>>>(ctx, ctx_bf);
  cvt_kernel<<<(DDIM * DDIM) / (256 * 8), 256, 0, stream>>>(W, W_bf);
  gemm_logits<<<(MDIM / 128) * (DDIM / 128), 256, 0, stream>>>(ctx_bf, W_bf, v, out_attn);
  softmax_kernel<<<BDIM, 256, 0, stream>>>(out_attn);
  wsum_kernel<<<BDIM * 16, 256, 0, stream>>>(ctx, out_attn, out_wc);
}